// Round 1
// baseline (1229.082 us; speedup 1.0000x reference)
//
#include <hip/hip_runtime.h>
#include <math.h>

#define BATCH   512
#define TSTEPS  3600
#define H       64
#define XCHUNK  16
#define NCHUNK  (TSTEPS / XCHUNK)   // 225
#define CLASSES 5

typedef _Float16 half8 __attribute__((ext_vector_type(8)));
typedef float    f32x4 __attribute__((ext_vector_type(4)));

__device__ __forceinline__ half8 bc_h8(uint4 v) {
    return __builtin_bit_cast(half8, v);
}

#define L2E 1.44269504088896f
#define S_N (2.0f * L2E)

// ONE WAVE per batch, MFMA GEMV, register-resident h exchange.
// vs R11 (1080 us): the per-step LDS round-trip (cvt -> ds_write_b16 ->
// in-order DS pipe -> 2x ds_read_b128 -> lgkmcnt drain, ~200+ cyc serial)
// is replaced by 8 PARALLEL ds_bpermute_b32: h is packed to f16 lane-pairs
// in-register (cvt + DPP quad-swap + parity select, ~12 cyc), then each
// lane gathers its two k-octets {8q..8q+7} and {32+8q..+7} directly from
// the producing lanes in one LDS-latency. Also: weights pre-scaled by
// -log2e (r,z) / +2log2e (n) so v_exp_f32 (=exp2) is used with no runtime
// scale muls; b_hh_n folded into the n-tile MFMA C operand (one fewer
// dependent add on the tanh path); x staged across lanes + readlane
// (kills the 16-reg double-buffer copies).
__global__ __launch_bounds__(64, 1) void gru_mfma_kernel(
    const float* __restrict__ x,      // [B, T, 1]
    const float* __restrict__ w_ih,   // [192, 1]
    const float* __restrict__ w_hh,   // [192, 64]
    const float* __restrict__ b_ih,   // [192]
    const float* __restrict__ b_hh,   // [192]
    const float* __restrict__ w_head, // [5, 64]
    const float* __restrict__ b_head, // [5]
    float* __restrict__ out)          // [B, 5]
{
    const int lane = threadIdx.x;    // block = 1 wave
    const int b    = blockIdx.x;
    const int q    = lane >> 4;      // k-octet / quadrant selector
    const int col  = lane & 15;      // B n-index / D col

    // --- B fragments: W_hh tiles, f16, pre-scaled for exp2-based gates.
    // B[k=8q+j][n=col] = sc * W[16t+col][32c+8q+j]
    half8 wB[12][2];
#pragma unroll
    for (int t = 0; t < 12; ++t) {
        const float sc = (t < 8) ? -L2E : S_N;   // r,z tiles : n tiles
#pragma unroll
        for (int c = 0; c < 2; ++c) {
            const float* wr = w_hh + (16 * t + col) * H + 32 * c + 8 * q;
            half8 f;
#pragma unroll
            for (int j = 0; j < 8; ++j) f[j] = (_Float16)(sc * wr[j]);
            wB[t][c] = f;
        }
    }

    // n-tile accumulator init = scaled b_hh_n (bias rides the MFMA C chain)
    f32x4 Cn[4];
#pragma unroll
    for (int t = 0; t < 4; ++t) {
        const float bn = S_N * b_hh[2 * H + 16 * t + col];
        Cn[t] = (f32x4){bn, bn, bn, bn};
    }

    // gate parameters for hidden index = lane (pre-scaled)
    const float wih_r = -L2E * w_ih[lane];
    const float wih_z = -L2E * w_ih[H + lane];
    const float wih_n =  S_N * w_ih[2 * H + lane];
    const float bsr = -L2E * (b_ih[lane] + b_hh[lane]);          // merged r bias
    const float bsz = -L2E * (b_ih[H + lane] + b_hh[H + lane]);  // merged z bias
    const float bin =  S_N * b_ih[2 * H + lane];                 // n input bias

    // bpermute byte-index of this quadrant's first packed h word:
    // P word m lives in lanes {2m, 2m+1}; A0 word r comes from lane 8q+2r.
    const int pidx = 32 * q;

    float h_reg = 0.0f;
    const float* xb = x + (size_t)b * TSTEPS;
    float vxc = xb[col];   // chunk of 16 x values staged in lanes 0..15

    const f32x4 Z = {0.f, 0.f, 0.f, 0.f};

    for (int tc = 0; tc < NCHUNK; ++tc) {
        const float* nxt = xb + ((tc + 1 < NCHUNK) ? (tc + 1) * XCHUNK : 0);
        const float vxn = nxt[col];

#pragma unroll
        for (int tt = 0; tt < XCHUNK; ++tt) {
            // ---- pack h to f16 pairs in-register ----
            const unsigned int vh =
                (unsigned int)__builtin_bit_cast(unsigned short, (_Float16)h_reg);
            const unsigned int nbw = (unsigned int)__builtin_amdgcn_update_dpp(
                (int)vh, (int)vh, 0xB1 /*quad_perm 1,0,3,2*/, 0xF, 0xF, false);
            const unsigned int plo = (lane & 1) ? nbw : vh;
            const unsigned int phi = (lane & 1) ? vh  : nbw;
            const unsigned int P   = plo | (phi << 16);

            // ---- wave exchange: 8 independent gathers, one LDS latency ----
            const unsigned int a00 = (unsigned int)__builtin_amdgcn_ds_bpermute(pidx,       (int)P);
            const unsigned int a01 = (unsigned int)__builtin_amdgcn_ds_bpermute(pidx + 8,   (int)P);
            const unsigned int a02 = (unsigned int)__builtin_amdgcn_ds_bpermute(pidx + 16,  (int)P);
            const unsigned int a03 = (unsigned int)__builtin_amdgcn_ds_bpermute(pidx + 24,  (int)P);
            const unsigned int a10 = (unsigned int)__builtin_amdgcn_ds_bpermute(pidx + 128, (int)P);
            const unsigned int a11 = (unsigned int)__builtin_amdgcn_ds_bpermute(pidx + 136, (int)P);
            const unsigned int a12 = (unsigned int)__builtin_amdgcn_ds_bpermute(pidx + 144, (int)P);
            const unsigned int a13 = (unsigned int)__builtin_amdgcn_ds_bpermute(pidx + 152, (int)P);
            const half8 A0 = bc_h8((uint4){a00, a01, a02, a03});  // k = 8q..8q+7 of h[0..31]
            const half8 A1 = bc_h8((uint4){a10, a11, a12, a13});  // k = 32+8q..+7

            // input-projection terms: off the critical path
            const float xt = __builtin_bit_cast(float,
                __builtin_amdgcn_readlane(__builtin_bit_cast(int, vxc), tt));
            const float ir  = fmaf(xt, wih_r, bsr);
            const float iz  = fmaf(xt, wih_z, bsz);
            const float in_ = fmaf(xt, wih_n, bin);

#define GEMV(t, d, C)                                                          \
            d = __builtin_amdgcn_mfma_f32_16x16x32_f16(A0, wB[t][0], C, 0, 0, 0); \
            d = __builtin_amdgcn_mfma_f32_16x16x32_f16(A1, wB[t][1], d, 0, 0, 0);

            // ---- r tiles first: sigmoid overlaps the z/n MFMAs ----
            f32x4 d0, d1, d2, d3;
            GEMV(0, d0, Z) GEMV(1, d1, Z) GEMV(2, d2, Z) GEMV(3, d3, Z)
            const float ghr = (q < 2) ? (q == 0 ? d0[0] : d1[0])
                                      : (q == 2 ? d2[0] : d3[0]);
            const float er = __builtin_amdgcn_exp2f(ir + ghr);     // 2^(-x*log2e)
            const float r  = __builtin_amdgcn_rcpf(1.0f + er);

            f32x4 e0, e1, e2, e3;
            GEMV(4, e0, Z) GEMV(5, e1, Z) GEMV(6, e2, Z) GEMV(7, e3, Z)
            const float ghz = (q < 2) ? (q == 0 ? e0[0] : e1[0])
                                      : (q == 2 ? e2[0] : e3[0]);
            const float ez = __builtin_amdgcn_exp2f(iz + ghz);
            const float z  = __builtin_amdgcn_rcpf(1.0f + ez);

            f32x4 g0, g1, g2, g3;
            GEMV(8, g0, Cn[0]) GEMV(9, g1, Cn[1]) GEMV(10, g2, Cn[2]) GEMV(11, g3, Cn[3])
            const float ghn = (q < 2) ? (q == 0 ? g0[0] : g1[0])
                                      : (q == 2 ? g2[0] : g3[0]);
#undef GEMV

            // n = tanh(y), e = 2^(2*log2e*y); bhn already inside ghn via Cn
            const float ev = __builtin_amdgcn_exp2f(fmaf(r, ghn, in_));
            const float nn = (ev - 1.0f) * __builtin_amdgcn_rcpf(ev + 1.0f);
            h_reg = fmaf(z, h_reg - nn, nn);   // (1-z)*n + z*h
        }
        vxc = vxn;
    }

    // ---- head: out[b][c] = w_head[c,:] . h + b_head[c] ----
#pragma unroll
    for (int cc = 0; cc < CLASSES; ++cc) {
        float v = h_reg * w_head[cc * H + lane];
#pragma unroll
        for (int off = 32; off > 0; off >>= 1)
            v += __shfl_down(v, off, 64);
        if (lane == 0) out[b * CLASSES + cc] = v + b_head[cc];
    }
}

extern "C" void kernel_launch(void* const* d_in, const int* in_sizes, int n_in,
                              void* d_out, int out_size, void* d_ws, size_t ws_size,
                              hipStream_t stream) {
    const float* x      = (const float*)d_in[0];
    const float* w_ih   = (const float*)d_in[1];
    const float* w_hh   = (const float*)d_in[2];
    const float* b_ih   = (const float*)d_in[3];
    const float* b_hh   = (const float*)d_in[4];
    const float* w_head = (const float*)d_in[5];
    const float* b_head = (const float*)d_in[6];
    float* out = (float*)d_out;

    gru_mfma_kernel<<<BATCH, 64, 0, stream>>>(x, w_ih, w_hh, b_ih, b_hh,
                                              w_head, b_head, out);
}

// Round 2
// 803.552 us; speedup vs baseline: 1.5296x; 1.5296x over previous
//
#include <hip/hip_runtime.h>
#include <math.h>

#define BATCH   512
#define TSTEPS  3600
#define H       64
#define XCHUNK  16
#define NCHUNK  (TSTEPS / XCHUNK)   // 225
#define CLASSES 5

typedef _Float16 half8 __attribute__((ext_vector_type(8)));
typedef float    f32x4 __attribute__((ext_vector_type(4)));

__device__ __forceinline__ half8 bc_h8(uint4 v) {
    return __builtin_bit_cast(half8, v);
}

#define L2E 1.44269504088896f
#define S_N (2.0f * L2E)

// FOUR WAVES per batch. R1 post-mortem: the bpermute exchange regressed
// (+100 cyc/step) -> DS RT is ~170 cyc, not 400. The dominant remaining
// cost is the single-wave MFMA segment: 24 issues at ~8-10 cyc cadence
// plus cndmask select trees that make each gate wait on ALL 4 tiles.
// Fix: wave w computes tile w of each gate (6 MFMAs/wave, concurrent on
// 4 SIMDs). One tile per gate per wave => rows-replicated D means every
// lane holds the tile's col-value directly in d[0]: selects GONE, each
// gate waits only on its own 2-MFMA chain. h exchange: double-buffered
// 2x128B LDS (write buf[p^1], read buf[p], one __syncthreads per step;
// parity is compile-time via the unrolled tt). Kept from R1: exp2
// pre-scaled weights (no runtime log2e muls), b_hh_n folded into the
// n-tile MFMA C operand, x staged across lanes + readlane.
__global__ __launch_bounds__(256, 1) void gru_mfma_kernel(
    const float* __restrict__ x,      // [B, T, 1]
    const float* __restrict__ w_ih,   // [192, 1]
    const float* __restrict__ w_hh,   // [192, 64]
    const float* __restrict__ b_ih,   // [192]
    const float* __restrict__ b_hh,   // [192]
    const float* __restrict__ w_head, // [5, 64]
    const float* __restrict__ b_head, // [5]
    float* __restrict__ out)          // [B, 5]
{
    __shared__ __align__(16) _Float16 hl[2][H];   // double-buffered h (f16)
    __shared__ float hf[H];                       // final h (f32) for head

    const int tid  = threadIdx.x;
    const int w    = tid >> 6;       // wave id: owns tile w of each gate
    const int lane = tid & 63;
    const int q    = lane >> 4;      // A k-octet selector
    const int col  = lane & 15;      // tile column
    const int b    = blockIdx.x;
    const int i    = 16 * w + col;   // this lane's hidden index (4x over q)

    // --- B fragments: gate tiles {w, 4+w, 8+w}, f16, exp2-pre-scaled.
    // B[k=8q+j][n=col] = sc * W[16T+col][32c+8q+j]
    half8 wR[2], wZ[2], wN[2];
#pragma unroll
    for (int c = 0; c < 2; ++c) {
        const float* pr = w_hh + (16 * w       + col) * H + 32 * c + 8 * q;
        const float* pz = w_hh + (16 * (4 + w) + col) * H + 32 * c + 8 * q;
        const float* pn = w_hh + (16 * (8 + w) + col) * H + 32 * c + 8 * q;
        half8 fr, fz, fn;
#pragma unroll
        for (int j = 0; j < 8; ++j) {
            fr[j] = (_Float16)(-L2E * pr[j]);
            fz[j] = (_Float16)(-L2E * pz[j]);
            fn[j] = (_Float16)( S_N * pn[j]);
        }
        wR[c] = fr; wZ[c] = fz; wN[c] = fn;
    }

    // n-tile bias rides the MFMA C chain (rows replicated -> same per reg)
    const float bn = S_N * b_hh[2 * H + i];
    const f32x4 Cn = {bn, bn, bn, bn};
    const f32x4 Z  = {0.f, 0.f, 0.f, 0.f};

    // gate parameters for hidden index i (pre-scaled)
    const float wih_r = -L2E * w_ih[i];
    const float wih_z = -L2E * w_ih[H + i];
    const float wih_n =  S_N * w_ih[2 * H + i];
    const float bsr = -L2E * (b_ih[i] + b_hh[i]);
    const float bsz = -L2E * (b_ih[H + i] + b_hh[H + i]);
    const float bin =  S_N * b_ih[2 * H + i];

    float h_reg = 0.0f;
    if (lane < 16) hl[0][16 * w + lane] = (_Float16)0.0f;  // h0 = 0
    __syncthreads();

    const float* xb = x + (size_t)b * TSTEPS;
    float vxc = xb[col];   // 16 x values staged in lanes 0..15 (per wave)

    for (int tc = 0; tc < NCHUNK; ++tc) {
        const float* nxt = xb + ((tc + 1 < NCHUNK) ? (tc + 1) * XCHUNK : 0);
        const float vxn = nxt[col];

#pragma unroll
        for (int tt = 0; tt < XCHUNK; ++tt) {
            // step s = tc*16+tt reads buf[s&1]=buf[tt&1], writes the other
            const uint4* hp = (const uint4*)hl[tt & 1];
            const half8 A0 = bc_h8(hp[q]);        // k = 8q..8q+7
            const half8 A1 = bc_h8(hp[4 + q]);    // k = 32+8q..32+8q+7

            const float xt = __builtin_bit_cast(float,
                __builtin_amdgcn_readlane(__builtin_bit_cast(int, vxc), tt));
            const float ir  = fmaf(xt, wih_r, bsr);
            const float iz  = fmaf(xt, wih_z, bsz);
            const float in_ = fmaf(xt, wih_n, bin);

            // 6 MFMAs, A0-half first (lets compiler split the lgkm wait)
            f32x4 dr, dz, dn;
            dr = __builtin_amdgcn_mfma_f32_16x16x32_f16(A0, wR[0], Z,  0, 0, 0);
            dz = __builtin_amdgcn_mfma_f32_16x16x32_f16(A0, wZ[0], Z,  0, 0, 0);
            dn = __builtin_amdgcn_mfma_f32_16x16x32_f16(A0, wN[0], Cn, 0, 0, 0);
            dr = __builtin_amdgcn_mfma_f32_16x16x32_f16(A1, wR[1], dr, 0, 0, 0);
            dz = __builtin_amdgcn_mfma_f32_16x16x32_f16(A1, wZ[1], dz, 0, 0, 0);
            dn = __builtin_amdgcn_mfma_f32_16x16x32_f16(A1, wN[1], dn, 0, 0, 0);

            // select-free tail: rows replicated => d[0] IS gh[i]
            const float er = __builtin_amdgcn_exp2f(ir + dr[0]);
            const float r  = __builtin_amdgcn_rcpf(1.0f + er);
            const float ez = __builtin_amdgcn_exp2f(iz + dz[0]);
            const float z  = __builtin_amdgcn_rcpf(1.0f + ez);
            const float ev = __builtin_amdgcn_exp2f(fmaf(r, dn[0], in_));
            const float nn = (ev - 1.0f) * __builtin_amdgcn_rcpf(ev + 1.0f);
            h_reg = fmaf(z, h_reg - nn, nn);      // (1-z)*n + z*h

            if (lane < 16) hl[(tt & 1) ^ 1][16 * w + lane] = (_Float16)h_reg;
            __syncthreads();
        }
        vxc = vxn;
    }

    // ---- head: out[b][c] = w_head[c,:] . h + b_head[c] ----
    if (lane < 16) hf[16 * w + lane] = h_reg;
    __syncthreads();
    if (w == 0) {
        const float hv = hf[lane];
#pragma unroll
        for (int cc = 0; cc < CLASSES; ++cc) {
            float v = hv * w_head[cc * H + lane];
#pragma unroll
            for (int off = 32; off > 0; off >>= 1)
                v += __shfl_down(v, off, 64);
            if (lane == 0) out[b * CLASSES + cc] = v + b_head[cc];
        }
    }
}

extern "C" void kernel_launch(void* const* d_in, const int* in_sizes, int n_in,
                              void* d_out, int out_size, void* d_ws, size_t ws_size,
                              hipStream_t stream) {
    const float* x      = (const float*)d_in[0];
    const float* w_ih   = (const float*)d_in[1];
    const float* w_hh   = (const float*)d_in[2];
    const float* b_ih   = (const float*)d_in[3];
    const float* b_hh   = (const float*)d_in[4];
    const float* w_head = (const float*)d_in[5];
    const float* b_head = (const float*)d_in[6];
    float* out = (float*)d_out;

    gru_mfma_kernel<<<BATCH, 256, 0, stream>>>(x, w_ih, w_hh, b_ih, b_hh,
                                               w_head, b_head, out);
}